// Round 1
// baseline (2410.882 us; speedup 1.0000x reference)
//
#include <hip/hip_runtime.h>

#define N_U 100000
#define N_R 50000
#define DIM 128
#define HID 64
#define NE  1000000

// ---------------------------------------------------------------------------
// proj: h[row][lane] = sum_k x[row][k] * W[k][lane]
// One wave per row, lane = output column (H=64 = wave size).
// W (128x64 f32 = 32 KiB) staged in LDS; Wlds[k*64+lane] across 64 lanes is
// 64 consecutive floats -> 2 lanes/bank -> conflict-free.
// ---------------------------------------------------------------------------
__global__ __launch_bounds__(256) void proj_kernel(
    const float* __restrict__ x, const float* __restrict__ W,
    float* __restrict__ h, int nrows)
{
    __shared__ float Wlds[DIM * HID];
    for (int i = threadIdx.x; i < DIM * HID; i += blockDim.x) Wlds[i] = W[i];
    __syncthreads();

    const int wave = threadIdx.x >> 6;
    const int lane = threadIdx.x & 63;
    const int row  = blockIdx.x * 4 + wave;
    if (row >= nrows) return;

    const float* xr = x + (size_t)row * DIM;
    float acc = 0.f;
#pragma unroll
    for (int k4 = 0; k4 < DIM / 4; ++k4) {
        float4 xv = *reinterpret_cast<const float4*>(xr + k4 * 4);
        acc = fmaf(xv.x, Wlds[(k4 * 4 + 0) * HID + lane], acc);
        acc = fmaf(xv.y, Wlds[(k4 * 4 + 1) * HID + lane], acc);
        acc = fmaf(xv.z, Wlds[(k4 * 4 + 2) * HID + lane], acc);
        acc = fmaf(xv.w, Wlds[(k4 * 4 + 3) * HID + lane], acc);
    }
    h[(size_t)row * HID + lane] = acc;
}

// ---------------------------------------------------------------------------
// scatter: agg[dst] += h[src] (64 f32 per edge), cnt[dst]++.
// 16 threads per edge, each does a float4 gather (coalesced 256B per edge)
// and 4 agent-scope fp32 atomics (global_atomic_add_f32, no CAS loop).
// ---------------------------------------------------------------------------
__global__ __launch_bounds__(256) void scatter_kernel(
    const float* __restrict__ h, const int* __restrict__ src,
    const int* __restrict__ dst, float* __restrict__ agg,
    int* __restrict__ cnt)
{
    const int gid = blockIdx.x * blockDim.x + threadIdx.x;
    const int e = gid >> 4;
    const int c = gid & 15;
    if (e >= NE) return;

    const int s = src[e];
    const int d = dst[e];
    float4 v = *reinterpret_cast<const float4*>(h + (size_t)s * HID + c * 4);
    float* a = agg + (size_t)d * HID + c * 4;
    __hip_atomic_fetch_add(&a[0], v.x, __ATOMIC_RELAXED, __HIP_MEMORY_SCOPE_AGENT);
    __hip_atomic_fetch_add(&a[1], v.y, __ATOMIC_RELAXED, __HIP_MEMORY_SCOPE_AGENT);
    __hip_atomic_fetch_add(&a[2], v.z, __ATOMIC_RELAXED, __HIP_MEMORY_SCOPE_AGENT);
    __hip_atomic_fetch_add(&a[3], v.w, __ATOMIC_RELAXED, __HIP_MEMORY_SCOPE_AGENT);
    if (c == 0) atomicAdd(&cnt[d], 1);
}

// ---------------------------------------------------------------------------
// epilogue: out[row][lane] = relu(agg[row][lane]/max(cnt,1) + b[lane]
//                                 + sum_k x[row][k]*Wr[k][lane])
// agg lives in `out` (accumulated there by scatter); overwritten in place.
// ---------------------------------------------------------------------------
__global__ __launch_bounds__(256) void epilogue_kernel(
    const float* __restrict__ x, const float* __restrict__ Wr,
    const float* __restrict__ b, const int* __restrict__ cnt,
    float* __restrict__ out, int nrows)
{
    __shared__ float Wlds[DIM * HID];
    __shared__ float blds[HID];
    for (int i = threadIdx.x; i < DIM * HID; i += blockDim.x) Wlds[i] = Wr[i];
    if (threadIdx.x < HID) blds[threadIdx.x] = b[threadIdx.x];
    __syncthreads();

    const int wave = threadIdx.x >> 6;
    const int lane = threadIdx.x & 63;
    const int row  = blockIdx.x * 4 + wave;
    if (row >= nrows) return;

    const float* xr = x + (size_t)row * DIM;
    float acc = 0.f;
#pragma unroll
    for (int k4 = 0; k4 < DIM / 4; ++k4) {
        float4 xv = *reinterpret_cast<const float4*>(xr + k4 * 4);
        acc = fmaf(xv.x, Wlds[(k4 * 4 + 0) * HID + lane], acc);
        acc = fmaf(xv.y, Wlds[(k4 * 4 + 1) * HID + lane], acc);
        acc = fmaf(xv.z, Wlds[(k4 * 4 + 2) * HID + lane], acc);
        acc = fmaf(xv.w, Wlds[(k4 * 4 + 3) * HID + lane], acc);
    }
    const size_t oi = (size_t)row * HID + lane;
    float inv = 1.0f / fmaxf((float)cnt[row], 1.0f);
    float v = out[oi] * inv + blds[lane] + acc;
    out[oi] = fmaxf(v, 0.0f);
}

extern "C" void kernel_launch(void* const* d_in, const int* in_sizes, int n_in,
                              void* d_out, int out_size, void* d_ws, size_t ws_size,
                              hipStream_t stream)
{
    const float* x_user = (const float*)d_in[0];
    const float* x_res  = (const float*)d_in[1];
    const int* ua_src   = (const int*)d_in[2];
    const int* ua_dst   = (const int*)d_in[3];
    const int* ru_src   = (const int*)d_in[4];
    const int* ru_dst   = (const int*)d_in[5];
    const float* W_l_ua = (const float*)d_in[6];
    const float* b_ua   = (const float*)d_in[7];
    const float* W_r_ua = (const float*)d_in[8];
    const float* W_l_ru = (const float*)d_in[9];
    const float* b_ru   = (const float*)d_in[10];
    const float* W_r_ru = (const float*)d_in[11];

    float* out_user = (float*)d_out;                       // [N_U, H]
    float* out_res  = out_user + (size_t)N_U * HID;        // [N_R, H]

    // workspace: h_user | h_res | cnt_res | cnt_user  (~39 MB)
    float* h_user  = (float*)d_ws;                         // N_U*H
    float* h_res   = h_user + (size_t)N_U * HID;           // N_R*H
    int*   cnt_res = (int*)(h_res + (size_t)N_R * HID);    // N_R
    int*   cnt_user = cnt_res + N_R;                       // N_U

    // zero the aggregation targets (d_out doubles as agg) and the counts
    hipMemsetAsync(d_out, 0, (size_t)(N_U + N_R) * HID * sizeof(float), stream);
    hipMemsetAsync(cnt_res, 0, (size_t)(N_R + N_U) * sizeof(int), stream);

    // 1) project sources into H-space:  h = x @ W_l
    proj_kernel<<<(N_U + 3) / 4, 256, 0, stream>>>(x_user, W_l_ua, h_user, N_U);
    proj_kernel<<<(N_R + 3) / 4, 256, 0, stream>>>(x_res,  W_l_ru, h_res,  N_R);

    // 2) scatter-sum projected features onto destinations (+ degree counts)
    const int sgrid = (NE * 16) / 256;  // 62500
    scatter_kernel<<<sgrid, 256, 0, stream>>>(h_user, ua_src, ua_dst, out_res,  cnt_res);
    scatter_kernel<<<sgrid, 256, 0, stream>>>(h_res,  ru_src, ru_dst, out_user, cnt_user);

    // 3) fused epilogue: mean-normalize + bias + self-term GEMM + ReLU
    epilogue_kernel<<<(N_R + 3) / 4, 256, 0, stream>>>(x_res,  W_r_ua, b_ua, cnt_res,  out_res,  N_R);
    epilogue_kernel<<<(N_U + 3) / 4, 256, 0, stream>>>(x_user, W_r_ru, b_ru, cnt_user, out_user, N_U);
}

// Round 2
// 432.019 us; speedup vs baseline: 5.5805x; 5.5805x over previous
//
#include <hip/hip_runtime.h>

#define N_U 100000
#define N_R 50000
#define DIM 128
#define HID 64
#define NE  1000000
#define N_TOT (N_R + N_U)          // 150000: deg/off/cur layout = [res | user]
#define NBLK ((N_TOT + 1023) / 1024) // 147 (must be <= 256 for scan_top)

// ---------------------------------------------------------------------------
// CSR build step 1: degree histogram (int atomics only)
// ---------------------------------------------------------------------------
__global__ __launch_bounds__(256) void hist_kernel(
    const int* __restrict__ dst, int* __restrict__ deg, int n, int base)
{
    int i = blockIdx.x * blockDim.x + threadIdx.x;
    if (i < n) atomicAdd(&deg[base + dst[i]], 1);
}

// ---------------------------------------------------------------------------
// CSR build step 2: exclusive scan over deg[N_TOT] (3-kernel standard scan)
// scan_block: per-block (1024 elems) local exclusive scan -> off, block total -> bsum
// ---------------------------------------------------------------------------
__global__ __launch_bounds__(256) void scan_block_kernel(
    const int* __restrict__ deg, int* __restrict__ off, int* __restrict__ bsum)
{
    __shared__ int tmp[256];
    const int t = threadIdx.x;
    const int i0 = blockIdx.x * 1024 + t * 4;
    int v0 = (i0 + 0 < N_TOT) ? deg[i0 + 0] : 0;
    int v1 = (i0 + 1 < N_TOT) ? deg[i0 + 1] : 0;
    int v2 = (i0 + 2 < N_TOT) ? deg[i0 + 2] : 0;
    int v3 = (i0 + 3 < N_TOT) ? deg[i0 + 3] : 0;
    int s = v0 + v1 + v2 + v3;
    tmp[t] = s;
    __syncthreads();
    for (int o = 1; o < 256; o <<= 1) {
        int v = (t >= o) ? tmp[t - o] : 0;
        __syncthreads();
        tmp[t] += v;
        __syncthreads();
    }
    int excl = tmp[t] - s;
    if (i0 + 0 < N_TOT) off[i0 + 0] = excl;
    if (i0 + 1 < N_TOT) off[i0 + 1] = excl + v0;
    if (i0 + 2 < N_TOT) off[i0 + 2] = excl + v0 + v1;
    if (i0 + 3 < N_TOT) off[i0 + 3] = excl + v0 + v1 + v2;
    if (t == 255) bsum[blockIdx.x] = excl + s;
}

__global__ __launch_bounds__(256) void scan_top_kernel(int* __restrict__ bsum)
{
    __shared__ int tmp[256];
    const int t = threadIdx.x;
    int s = (t < NBLK) ? bsum[t] : 0;
    tmp[t] = s;
    __syncthreads();
    for (int o = 1; o < 256; o <<= 1) {
        int v = (t >= o) ? tmp[t - o] : 0;
        __syncthreads();
        tmp[t] += v;
        __syncthreads();
    }
    if (t < NBLK) bsum[t] = tmp[t] - s;
}

__global__ __launch_bounds__(256) void scan_add_kernel(
    int* __restrict__ off, int* __restrict__ cur, const int* __restrict__ bsum)
{
    const int bs = bsum[blockIdx.x];
    const int i0 = blockIdx.x * 1024 + threadIdx.x * 4;
#pragma unroll
    for (int l = 0; l < 4; ++l) {
        int i = i0 + l;
        if (i < N_TOT) {
            int v = off[i] + bs;
            off[i] = v;
            cur[i] = v;
        }
    }
}

// ---------------------------------------------------------------------------
// CSR build step 3: fill column (src) lists via per-row cursors
// Offsets are global across both graphs, so col slots partition exactly.
// ---------------------------------------------------------------------------
__global__ __launch_bounds__(256) void fill_kernel(
    const int* __restrict__ src, const int* __restrict__ dst,
    int* __restrict__ cur, int* __restrict__ col, int n, int base)
{
    int i = blockIdx.x * blockDim.x + threadIdx.x;
    if (i < n) {
        int p = atomicAdd(&cur[base + dst[i]], 1);
        col[p] = src[i];
    }
}

// ---------------------------------------------------------------------------
// proj: h = x @ W  ([nrows x 128] @ [128 x 64])
// Block = 256 threads handles 64 rows x 64 cols. Thread = 4 rows x 4 cols
// register tile: per 4 k's, 8 ds_read_b128 feed 64 FMAs (vs 1 b32 per FMA
// in the naive lane=col structure). x staged in LDS padded to stride 132
// (keeps 16B alignment; 2-way bank aliasing = free per m136). W reads are
// 16 distinct 16B addresses covering all 32 banks -> conflict-free.
// ---------------------------------------------------------------------------
__global__ __launch_bounds__(256) void proj_kernel(
    const float* __restrict__ x, const float* __restrict__ W,
    float* __restrict__ h, int nrows)
{
    __shared__ float Wl[DIM * HID];        // 32 KB
    __shared__ float xs[64][DIM + 4];      // 33 KB, stride 132 floats
    const int tid = threadIdx.x;
    const int rowbase = blockIdx.x * 64;

    {   // stage W (2048 float4, coalesced)
        const float4* Wv = (const float4*)W;
        float4* Wd = (float4*)Wl;
        for (int i = tid; i < DIM * HID / 4; i += 256) Wd[i] = Wv[i];
    }
    // stage x: 64 rows x 32 float4 (coalesced), zero-fill past nrows
    for (int i = tid; i < 64 * 32; i += 256) {
        int r = i >> 5, c4 = i & 31;
        float4 v = make_float4(0.f, 0.f, 0.f, 0.f);
        if (rowbase + r < nrows)
            v = *(const float4*)(x + (size_t)(rowbase + r) * DIM + c4 * 4);
        *(float4*)(&xs[r][c4 * 4]) = v;
    }
    __syncthreads();

    const int cg = tid & 15;   // col group: cols [cg*4, cg*4+3]
    const int rg = tid >> 4;   // row group: rows [rg*4, rg*4+3]
    float4 a0 = {0,0,0,0}, a1 = {0,0,0,0}, a2 = {0,0,0,0}, a3 = {0,0,0,0};

#define FMA4(acc, xk, wv) \
    acc.x = fmaf(xk, wv.x, acc.x); acc.y = fmaf(xk, wv.y, acc.y); \
    acc.z = fmaf(xk, wv.z, acc.z); acc.w = fmaf(xk, wv.w, acc.w);

    for (int k4 = 0; k4 < DIM / 4; ++k4) {
        float4 x0 = *(const float4*)&xs[rg * 4 + 0][k4 * 4];
        float4 x1 = *(const float4*)&xs[rg * 4 + 1][k4 * 4];
        float4 x2 = *(const float4*)&xs[rg * 4 + 2][k4 * 4];
        float4 x3 = *(const float4*)&xs[rg * 4 + 3][k4 * 4];
        float4 w0 = *(const float4*)&Wl[(k4 * 4 + 0) * HID + cg * 4];
        float4 w1 = *(const float4*)&Wl[(k4 * 4 + 1) * HID + cg * 4];
        float4 w2 = *(const float4*)&Wl[(k4 * 4 + 2) * HID + cg * 4];
        float4 w3 = *(const float4*)&Wl[(k4 * 4 + 3) * HID + cg * 4];
        FMA4(a0, x0.x, w0) FMA4(a1, x1.x, w0) FMA4(a2, x2.x, w0) FMA4(a3, x3.x, w0)
        FMA4(a0, x0.y, w1) FMA4(a1, x1.y, w1) FMA4(a2, x2.y, w1) FMA4(a3, x3.y, w1)
        FMA4(a0, x0.z, w2) FMA4(a1, x1.z, w2) FMA4(a2, x2.z, w2) FMA4(a3, x3.z, w2)
        FMA4(a0, x0.w, w3) FMA4(a1, x1.w, w3) FMA4(a2, x2.w, w3) FMA4(a3, x3.w, w3)
    }
#undef FMA4

    const int r0 = rowbase + rg * 4;
    if (r0 + 0 < nrows) *(float4*)(h + (size_t)(r0 + 0) * HID + cg * 4) = a0;
    if (r0 + 1 < nrows) *(float4*)(h + (size_t)(r0 + 1) * HID + cg * 4) = a1;
    if (r0 + 2 < nrows) *(float4*)(h + (size_t)(r0 + 2) * HID + cg * 4) = a2;
    if (r0 + 3 < nrows) *(float4*)(h + (size_t)(r0 + 3) * HID + cg * 4) = a3;
}

// ---------------------------------------------------------------------------
// gather_finalize: out[row] = relu( mean_{s in col[row]} h[s] + b + out[row] )
// (out already holds the self-term x_dst @ W_r from proj.)
// One wave per row; each edge = one coalesced 256 B load of h[s][0..63].
// Unroll-4 keeps 4 gathers in flight.
// ---------------------------------------------------------------------------
__global__ __launch_bounds__(256) void gather_finalize_kernel(
    const float* __restrict__ h, const int* __restrict__ col,
    const int* __restrict__ off, const int* __restrict__ deg,
    const float* __restrict__ b, float* __restrict__ out, int base, int nrows)
{
    const int wave = threadIdx.x >> 6;
    const int lane = threadIdx.x & 63;
    const int row = blockIdx.x * 4 + wave;
    if (row >= nrows) return;

    const int o = off[base + row];
    const int d = deg[base + row];
    float acc = 0.f;
    int j = 0;
    for (; j + 4 <= d; j += 4) {
        int s0 = col[o + j + 0], s1 = col[o + j + 1];
        int s2 = col[o + j + 2], s3 = col[o + j + 3];
        float v0 = h[(size_t)s0 * HID + lane];
        float v1 = h[(size_t)s1 * HID + lane];
        float v2 = h[(size_t)s2 * HID + lane];
        float v3 = h[(size_t)s3 * HID + lane];
        acc += v0 + v1 + v2 + v3;
    }
    for (; j < d; ++j) acc += h[(size_t)col[o + j] * HID + lane];

    const size_t oi = (size_t)row * HID + lane;
    float v = acc / fmaxf((float)d, 1.f) + b[lane] + out[oi];
    out[oi] = fmaxf(v, 0.f);
}

extern "C" void kernel_launch(void* const* d_in, const int* in_sizes, int n_in,
                              void* d_out, int out_size, void* d_ws, size_t ws_size,
                              hipStream_t stream)
{
    const float* x_user = (const float*)d_in[0];
    const float* x_res  = (const float*)d_in[1];
    const int* ua_src   = (const int*)d_in[2];
    const int* ua_dst   = (const int*)d_in[3];
    const int* ru_src   = (const int*)d_in[4];
    const int* ru_dst   = (const int*)d_in[5];
    const float* W_l_ua = (const float*)d_in[6];
    const float* b_ua   = (const float*)d_in[7];
    const float* W_r_ua = (const float*)d_in[8];
    const float* W_l_ru = (const float*)d_in[9];
    const float* b_ru   = (const float*)d_in[10];
    const float* W_r_ru = (const float*)d_in[11];

    float* out_user = (float*)d_out;                    // [N_U, H]
    float* out_res  = out_user + (size_t)N_U * HID;     // [N_R, H]

    // workspace layout (~48 MB)
    float* h_user = (float*)d_ws;                       // N_U*H
    float* h_res  = h_user + (size_t)N_U * HID;         // N_R*H
    int* deg  = (int*)(h_res + (size_t)N_R * HID);      // N_TOT
    int* off  = deg + N_TOT;                            // N_TOT
    int* cur  = off + N_TOT;                            // N_TOT
    int* bsum = cur + N_TOT;                            // 256
    int* col  = bsum + 256;                             // 2*NE

    const int egrid = (NE + 255) / 256;

    // --- CSR build ---
    hipMemsetAsync(deg, 0, (size_t)N_TOT * sizeof(int), stream);
    hist_kernel<<<egrid, 256, 0, stream>>>(ua_dst, deg, NE, 0);
    hist_kernel<<<egrid, 256, 0, stream>>>(ru_dst, deg, NE, N_R);
    scan_block_kernel<<<NBLK, 256, 0, stream>>>(deg, off, bsum);
    scan_top_kernel<<<1, 256, 0, stream>>>(bsum);
    scan_add_kernel<<<NBLK, 256, 0, stream>>>(off, cur, bsum);
    fill_kernel<<<egrid, 256, 0, stream>>>(ua_src, ua_dst, cur, col, NE, 0);
    fill_kernel<<<egrid, 256, 0, stream>>>(ru_src, ru_dst, cur, col, NE, N_R);

    // --- projections (neighbor terms into ws, self terms into d_out) ---
    proj_kernel<<<(N_U + 63) / 64, 256, 0, stream>>>(x_user, W_l_ua, h_user, N_U);
    proj_kernel<<<(N_R + 63) / 64, 256, 0, stream>>>(x_res,  W_l_ru, h_res,  N_R);
    proj_kernel<<<(N_R + 63) / 64, 256, 0, stream>>>(x_res,  W_r_ua, out_res,  N_R);
    proj_kernel<<<(N_U + 63) / 64, 256, 0, stream>>>(x_user, W_r_ru, out_user, N_U);

    // --- gather + mean + bias + self + relu ---
    gather_finalize_kernel<<<(N_R + 3) / 4, 256, 0, stream>>>(
        h_user, col, off, deg, b_ua, out_res, 0, N_R);
    gather_finalize_kernel<<<(N_U + 3) / 4, 256, 0, stream>>>(
        h_res, col, off, deg, b_ru, out_user, N_R, N_U);
}